// Round 7
// baseline (212.209 us; speedup 1.0000x reference)
//
#include <hip/hip_runtime.h>
#include <math.h>

#define BATCH 2
#define SEQ   2048
#define DMODEL 1024
#define NHEAD 16
#define HEADD 64
#define MROWS 4096

typedef __attribute__((ext_vector_type(8))) __bf16 bf16x8;
typedef __attribute__((ext_vector_type(4))) float f32x4;

__device__ __forceinline__ ushort f2bf(float f) {
    uint u = __float_as_uint(f);
    u += 0x7fffu + ((u >> 16) & 1u);
    return (ushort)(u >> 16);
}
__device__ __forceinline__ float bf2f(ushort h) {
    return __uint_as_float(((uint)h) << 16);
}
__device__ __forceinline__ ushort4 pack4bf(float a, float b, float c, float d) {
    union { __bf16 h[4]; ushort4 u; } p;
    p.h[0] = (__bf16)a; p.h[1] = (__bf16)b; p.h[2] = (__bf16)c; p.h[3] = (__bf16)d;
    return p.u;
}
__device__ __forceinline__ float vmax4(const f32x4 v) {
    return fmaxf(fmaxf(v[0], v[1]), fmaxf(v[2], v[3]));
}

#define GLD16(gsrc, ldst)                                                         \
    __builtin_amdgcn_global_load_lds(                                             \
        (const __attribute__((address_space(1))) unsigned int*)(gsrc),            \
        (__attribute__((address_space(3))) unsigned int*)(ldst), 16, 0, 0)

// Q pre-scale: (1/sqrt(64)) * log2(e)  -> softmax in exp2 domain
#define QSCALE 0.1803368801111204f

// ---------------- prep: x fp32 -> bf16 (hi only) ----------------
__global__ __launch_bounds__(256) void split_x(const float* __restrict__ in,
                                               ushort* __restrict__ oh, int n4) {
    int i = blockIdx.x * 256 + threadIdx.x;
    const int stride = gridDim.x * 256;
    for (; i < n4; i += stride) {
        const float4 v = reinterpret_cast<const float4*>(in)[i];
        ushort4 h;
        h.x = f2bf(v.x); h.y = f2bf(v.y); h.z = f2bf(v.z); h.w = f2bf(v.w);
        reinterpret_cast<ushort4*>(oh)[i] = h;
    }
}

// ---------------- prep: W^T; z<3 -> combined QKV hi; z==3 -> Wo hi/lo ----------------
__global__ __launch_bounds__(256) void tsplit_w(const float* __restrict__ Wq,
                                                const float* __restrict__ Wk,
                                                const float* __restrict__ Wv,
                                                const float* __restrict__ Wo,
                                                ushort* __restrict__ wtc,
                                                ushort* __restrict__ woh,
                                                ushort* __restrict__ wol) {
    const int z = blockIdx.z;
    const float* W = (z == 0) ? Wq : (z == 1) ? Wk : (z == 2) ? Wv : Wo;
    __shared__ float T[64][68];
    const int t = threadIdx.x;
    const int k0 = blockIdx.y * 64, n0 = blockIdx.x * 64;
    {
        const int r = t >> 2, c0 = (t & 3) * 16;
        #pragma unroll
        for (int j = 0; j < 4; ++j)
            *reinterpret_cast<float4*>(&T[r][c0 + j * 4]) =
                *reinterpret_cast<const float4*>(&W[(size_t)(k0 + r) * DMODEL + n0 + c0 + j * 4]);
    }
    __syncthreads();
    const int nl = t >> 2, kq = t & 3;
    if (z < 3) {
        ushort hb[16];
        #pragma unroll
        for (int e = 0; e < 16; ++e) hb[e] = f2bf(T[kq * 16 + e][nl]);
        const size_t o = (size_t)(z * 1024 + n0 + nl) * DMODEL + k0 + kq * 16;
        *reinterpret_cast<uint4*>(&wtc[o]) = *reinterpret_cast<uint4*>(&hb[0]);
        *reinterpret_cast<uint4*>(&wtc[o + 8]) = *reinterpret_cast<uint4*>(&hb[8]);
    } else {
        ushort hb[16], lb[16];
        #pragma unroll
        for (int e = 0; e < 16; ++e) {
            const float v = T[kq * 16 + e][nl];
            const ushort h = f2bf(v);
            hb[e] = h; lb[e] = f2bf(v - bf2f(h));
        }
        const size_t o = (size_t)(n0 + nl) * DMODEL + k0 + kq * 16;
        *reinterpret_cast<uint4*>(&woh[o]) = *reinterpret_cast<uint4*>(&hb[0]);
        *reinterpret_cast<uint4*>(&woh[o + 8]) = *reinterpret_cast<uint4*>(&hb[8]);
        *reinterpret_cast<uint4*>(&wol[o]) = *reinterpret_cast<uint4*>(&lb[0]);
        *reinterpret_cast<uint4*>(&wol[o + 8]) = *reinterpret_cast<uint4*>(&lb[8]);
    }
}

// ---------------- fused QKV GEMM: single-pass bf16, 128x128 tile, BK=64 ----------------
__global__ __launch_bounds__(512) void gemm_qkv(const ushort* __restrict__ xh,
                                                const ushort* __restrict__ wtc,
                                                ushort* __restrict__ Qb,
                                                ushort* __restrict__ Kb,
                                                ushort* __restrict__ Vtb) {
    __shared__ ushort SH[17408];
    ushort* const Ah = SH;
    ushort* const Bh = SH + 8192;

    const int t = threadIdx.x, lane = t & 63, w = t >> 6;
    const int l = lane & 15, g = lane >> 4;
    const int wm = w >> 2, wn = w & 3;
    const int bm = blockIdx.y * 128, bn = blockIdx.x * 128;

    f32x4 acc[4][2];
    #pragma unroll
    for (int mt = 0; mt < 4; ++mt)
        #pragma unroll
        for (int nt = 0; nt < 2; ++nt) acc[mt][nt] = (f32x4){0.f, 0.f, 0.f, 0.f};

    for (int kt = 0; kt < DMODEL; kt += 64) {
        __syncthreads();
        #pragma unroll
        for (int i = 0; i < 4; ++i) {
            const int sid = w * 4 + i;
            const int c = sid & 15;
            const ushort* src = (sid < 16) ? xh : wtc;
            const int rb = (sid < 16) ? bm : bn;
            ushort* dst = ((sid < 16) ? Ah : Bh) + c * 512;
            const int row = c * 8 + (lane >> 3);
            const int sw = ((lane & 7) ^ (row & 7)) << 3;
            GLD16(src + (size_t)(rb + row) * DMODEL + kt + sw, dst);
        }
        __syncthreads();

        bf16x8 af[4][2], bf[2][2];
        #pragma unroll
        for (int mt = 0; mt < 4; ++mt)
            #pragma unroll
            for (int s = 0; s < 2; ++s) {
                const int m = wm * 64 + mt * 16 + l;
                af[mt][s] = *reinterpret_cast<const bf16x8*>(&Ah[m * 64 + (((g + 4 * s) ^ (m & 7)) << 3)]);
            }
        #pragma unroll
        for (int nt = 0; nt < 2; ++nt)
            #pragma unroll
            for (int s = 0; s < 2; ++s) {
                const int n = wn * 32 + nt * 16 + l;
                bf[nt][s] = *reinterpret_cast<const bf16x8*>(&Bh[n * 64 + (((g + 4 * s) ^ (n & 7)) << 3)]);
            }
        #pragma unroll
        for (int mt = 0; mt < 4; ++mt)
            #pragma unroll
            for (int nt = 0; nt < 2; ++nt)
                #pragma unroll
                for (int s = 0; s < 2; ++s)
                    acc[mt][nt] = __builtin_amdgcn_mfma_f32_16x16x32_bf16(af[mt][s], bf[nt][s], acc[mt][nt], 0, 0, 0);
    }

    const int mode = bn >> 10;
    if (mode == 0) {
        #pragma unroll
        for (int mt = 0; mt < 4; ++mt)
            #pragma unroll
            for (int nt = 0; nt < 2; ++nt)
                #pragma unroll
                for (int r = 0; r < 4; ++r) {
                    const int row = bm + wm * 64 + mt * 16 + g * 4 + r;
                    const int col = bn + wn * 32 + nt * 16 + l;
                    Qb[(size_t)row * DMODEL + col] = f2bf(acc[mt][nt][r] * QSCALE);
                }
    } else if (mode == 1) {
        #pragma unroll
        for (int mt = 0; mt < 4; ++mt)
            #pragma unroll
            for (int nt = 0; nt < 2; ++nt)
                #pragma unroll
                for (int r = 0; r < 4; ++r) {
                    const int row = bm + wm * 64 + mt * 16 + g * 4 + r;
                    const int col = (bn - 1024) + wn * 32 + nt * 16 + l;
                    Kb[(size_t)row * DMODEL + col] = f2bf(acc[mt][nt][r]);
                }
    } else {
        __syncthreads();
        ushort* VtL = SH;   // [128 d][136 key]
        #pragma unroll
        for (int mt = 0; mt < 4; ++mt)
            #pragma unroll
            for (int nt = 0; nt < 2; ++nt)
                #pragma unroll
                for (int r = 0; r < 4; ++r) {
                    const int dl = wn * 32 + nt * 16 + l;
                    const int kl = wm * 64 + mt * 16 + g * 4 + r;
                    VtL[dl * 136 + kl] = f2bf(acc[mt][nt][r]);
                }
        __syncthreads();
        const int dl = t >> 2, kq = t & 3;
        const int b = bm >> 11;
        const int row = b * 1024 + (bn - 2048) + dl;
        const int key0 = bm & 2047;
        const size_t o = (size_t)row * SEQ + key0 + kq * 32;
        #pragma unroll
        for (int j = 0; j < 4; ++j)
            *reinterpret_cast<uint4*>(&Vtb[o + j * 8]) =
                *reinterpret_cast<uint4*>(&VtL[dl * 136 + kq * 32 + j * 8]);
    }
}

// ---------------- attention: split-K flash, paired tiles, LSE combine ----------------
// Block = 256 thr (4 waves). All waves own the SAME 16 rows of tile tA + 16 rows
// of tile tB (pair = gx>>2, row-group = gx&3) but process every-4th key chunk with
// private m/l/acc. One barrier, then exact log-sum-exp combine in LDS.
#define NSPLIT 4
#define LDP 72
#define OAW 68   // padded combine row stride (floats)

__global__ __launch_bounds__(256, 4) void attn(const ushort* __restrict__ Q,
                                               const ushort* __restrict__ K,
                                               const ushort* __restrict__ Vt,
                                               ushort* __restrict__ ATh,
                                               ushort* __restrict__ ATl) {
    __shared__ float OA[NSPLIT * 2 * 16 * OAW];   // 34.8KB; loop-time alias: P tiles
    __shared__ float ML[NSPLIT * 2 * 16 * 2];     // m,l partials
    ushort* const Pl = (ushort*)OA;               // [wave][32 rows][LDP] = 18.4KB

    const int t = threadIdx.x, lane = t & 63, s = t >> 6;   // s = split id
    const int l = lane & 15, g = lane >> 4;
    const int gx = blockIdx.x;
    const int pair = gx >> 2, rg = gx & 3;
    const int tA = pair, tB = 31 - pair;
    const int bh = blockIdx.y, b = bh >> 4, h = bh & 15;
    const size_t kbase = (size_t)b * SEQ * DMODEL + h * 64;
    const size_t vbase = (size_t)bh * 64 * SEQ;
    const int qrow0[2] = {tA * 64 + rg * 16, tB * 64 + rg * 16};
    const int nch[2] = {tA + 1, tB + 1};          // nch[0] <= 16 < nch[1]

    // Q B-operand frags (col=q=lane&15, k=d=32s+8g+e)
    bf16x8 qf[2][2];
    #pragma unroll
    for (int qs = 0; qs < 2; ++qs) {
        const size_t qo = (size_t)(b * SEQ + qrow0[qs] + l) * DMODEL + h * 64 + 8 * g;
        qf[qs][0] = *reinterpret_cast<const bf16x8*>(&Q[qo]);
        qf[qs][1] = *reinterpret_cast<const bf16x8*>(&Q[qo + 32]);
    }

    f32x4 accO[2][4];
    #pragma unroll
    for (int qs = 0; qs < 2; ++qs)
        #pragma unroll
        for (int dt = 0; dt < 4; ++dt) accO[qs][dt] = (f32x4){0.f, 0.f, 0.f, 0.f};
    float m_i[2] = {-INFINITY, -INFINITY}, l_i[2] = {0.f, 0.f};

    for (int kc = s; kc < nch[1]; kc += NSPLIT) {
        const int k0 = kc * 64;
        const bool doA = (kc < nch[0]);

        // K frags
        bf16x8 kf[4][2];
        #pragma unroll
        for (int nt = 0; nt < 4; ++nt) {
            const size_t ko = kbase + (size_t)(k0 + nt * 16 + l) * DMODEL + 8 * g;
            kf[nt][0] = *reinterpret_cast<const bf16x8*>(&K[ko]);
            kf[nt][1] = *reinterpret_cast<const bf16x8*>(&K[ko + 32]);
        }

        // swapped QK^T: sc[qs][nt][r] = score[key=k0+16nt+4g+r][q=qrow0+l]
        f32x4 sc[2][4];
        #pragma unroll
        for (int nt = 0; nt < 4; ++nt) {
            f32x4 z = (f32x4){0.f, 0.f, 0.f, 0.f};
            z = __builtin_amdgcn_mfma_f32_16x16x32_bf16(kf[nt][0], qf[1][0], z, 0, 0, 0);
            z = __builtin_amdgcn_mfma_f32_16x16x32_bf16(kf[nt][1], qf[1][1], z, 0, 0, 0);
            sc[1][nt] = z;
        }
        if (doA) {
            #pragma unroll
            for (int nt = 0; nt < 4; ++nt) {
                f32x4 z = (f32x4){0.f, 0.f, 0.f, 0.f};
                z = __builtin_amdgcn_mfma_f32_16x16x32_bf16(kf[nt][0], qf[0][0], z, 0, 0, 0);
                z = __builtin_amdgcn_mfma_f32_16x16x32_bf16(kf[nt][1], qf[0][1], z, 0, 0, 0);
                sc[0][nt] = z;
            }
        }

        // causal mask on each set's diagonal chunk
        #pragma unroll
        for (int qs = 0; qs < 2; ++qs) {
            if (kc == nch[qs] - 1) {
                const int qg = qrow0[qs] + l;
                #pragma unroll
                for (int nt = 0; nt < 4; ++nt)
                    #pragma unroll
                    for (int r = 0; r < 4; ++r)
                        if (k0 + nt * 16 + g * 4 + r > qg) sc[qs][nt][r] = -INFINITY;
            }
        }

        // V frags issued here: latency hides under the two softmax phases
        bf16x8 vf[4][2];
        #pragma unroll
        for (int dt = 0; dt < 4; ++dt) {
            const size_t vo = vbase + (size_t)(dt * 16 + l) * SEQ + k0 + 8 * g;
            vf[dt][0] = *reinterpret_cast<const bf16x8*>(&Vt[vo]);
            vf[dt][1] = *reinterpret_cast<const bf16x8*>(&Vt[vo + 32]);
        }

        // online softmax (exp2 domain), tree reductions, per active set
        #pragma unroll
        for (int qs = 0; qs < 2; ++qs) {
            if (qs == 0 && !doA) continue;
            float mc = fmaxf(fmaxf(vmax4(sc[qs][0]), vmax4(sc[qs][1])),
                             fmaxf(vmax4(sc[qs][2]), vmax4(sc[qs][3])));
            mc = fmaxf(mc, __shfl_xor(mc, 16, 64));
            mc = fmaxf(mc, __shfl_xor(mc, 32, 64));

            if (__any(mc > m_i[qs] + 8.f)) {          // defer-max rescale
                const float mn = fmaxf(m_i[qs], mc);
                const float al = exp2f(m_i[qs] - mn);
                m_i[qs] = mn;
                l_i[qs] *= al;
                #pragma unroll
                for (int r = 0; r < 4; ++r) {
                    const float ar = __shfl(al, 4 * g + r, 64);
                    #pragma unroll
                    for (int dt = 0; dt < 4; ++dt) accO[qs][dt][r] *= ar;
                }
            }

            float psum[4];
            #pragma unroll
            for (int nt = 0; nt < 4; ++nt) {
                #pragma unroll
                for (int r = 0; r < 4; ++r)
                    sc[qs][nt][r] = exp2f(sc[qs][nt][r] - m_i[qs]);
                psum[nt] = (sc[qs][nt][0] + sc[qs][nt][1]) + (sc[qs][nt][2] + sc[qs][nt][3]);
            }
            float rs = (psum[0] + psum[1]) + (psum[2] + psum[3]);
            rs += __shfl_xor(rs, 16, 64);
            rs += __shfl_xor(rs, 32, 64);
            l_i[qs] += rs;

            const int prow = s * 32 + qs * 16 + l;
            #pragma unroll
            for (int nt = 0; nt < 4; ++nt)
                *reinterpret_cast<ushort4*>(&Pl[prow * LDP + nt * 16 + 4 * g]) =
                    pack4bf(sc[qs][nt][0], sc[qs][nt][1], sc[qs][nt][2], sc[qs][nt][3]);
        }

        // PV
        #pragma unroll
        for (int qs = 0; qs < 2; ++qs) {
            if (qs == 0 && !doA) continue;
            bf16x8 pf[2];
            const int prow = s * 32 + qs * 16 + l;
            pf[0] = *reinterpret_cast<const bf16x8*>(&Pl[prow * LDP + 8 * g]);
            pf[1] = *reinterpret_cast<const bf16x8*>(&Pl[prow * LDP + 32 + 8 * g]);
            #pragma unroll
            for (int dt = 0; dt < 4; ++dt) {
                accO[qs][dt] = __builtin_amdgcn_mfma_f32_16x16x32_bf16(pf[0], vf[dt][0], accO[qs][dt], 0, 0, 0);
                accO[qs][dt] = __builtin_amdgcn_mfma_f32_16x16x32_bf16(pf[1], vf[dt][1], accO[qs][dt], 0, 0, 0);
            }
        }
    }

    __syncthreads();   // all P usage done; OA overwrite now safe

    // write partials: OA[split][qs][q][d], ML[split][qs][q] = {m, l}
    #pragma unroll
    for (int qs = 0; qs < 2; ++qs)
        #pragma unroll
        for (int dt = 0; dt < 4; ++dt)
            #pragma unroll
            for (int r = 0; r < 4; ++r)
                OA[((s * 2 + qs) * 16 + 4 * g + r) * OAW + dt * 16 + l] = accO[qs][dt][r];
    if (g == 0) {
        #pragma unroll
        for (int qs = 0; qs < 2; ++qs) {
            ML[((s * 2 + qs) * 16 + l) * 2 + 0] = m_i[qs];
            ML[((s * 2 + qs) * 16 + l) * 2 + 1] = l_i[qs];
        }
    }
    __syncthreads();

    // combine: 2048 outputs, 8 contiguous d per thread
    {
        const int o = t * 8;
        const int cqs = o >> 10, cq = (o >> 6) & 15, d0 = o & 63;
        float wgt[NSPLIT];
        float mstar = -INFINITY;
        #pragma unroll
        for (int si = 0; si < NSPLIT; ++si) {
            wgt[si] = ML[((si * 2 + cqs) * 16 + cq) * 2 + 0];
            mstar = fmaxf(mstar, wgt[si]);
        }
        float lstar = 0.f;
        #pragma unroll
        for (int si = 0; si < NSPLIT; ++si) {
            const float wv = exp2f(wgt[si] - mstar);
            wgt[si] = wv;
            lstar += wv * ML[((si * 2 + cqs) * 16 + cq) * 2 + 1];
        }
        float acc8[8] = {};
        #pragma unroll
        for (int si = 0; si < NSPLIT; ++si) {
            const float wv = wgt[si];
            const float* src = &OA[((si * 2 + cqs) * 16 + cq) * OAW + d0];
            #pragma unroll
            for (int j = 0; j < 8; ++j) acc8[j] += wv * src[j];
        }
        const float inv = 1.f / lstar;
        const int rowg = (cqs == 0 ? tA : tB) * 64 + rg * 16 + cq;
        const size_t obase = (size_t)(b * SEQ + rowg) * DMODEL + h * 64 + d0;
        ushort h8[8], l8[8];
        #pragma unroll
        for (int j = 0; j < 8; ++j) {
            const float val = acc8[j] * inv;
            h8[j] = f2bf(val);
            l8[j] = f2bf(val - bf2f(h8[j]));
        }
        *reinterpret_cast<uint4*>(&ATh[obase]) = *reinterpret_cast<uint4*>(&h8[0]);
        *reinterpret_cast<uint4*>(&ATl[obase]) = *reinterpret_cast<uint4*>(&l8[0]);
    }
}

// ---------------- out GEMM: 3-pass hi/lo, 128x64 tile, BK=64, fp32 out ----------------
__global__ __launch_bounds__(512) void gemm_o(const ushort* __restrict__ Ahg,
                                              const ushort* __restrict__ Alg,
                                              const ushort* __restrict__ Bhg,
                                              const ushort* __restrict__ Blg,
                                              float* __restrict__ C) {
    __shared__ ushort SH[24576];
    ushort* const Ah = SH;
    ushort* const Al = SH + 8192;
    ushort* const Bh = SH + 16384;
    ushort* const Bl = SH + 20480;

    const int t = threadIdx.x, lane = t & 63, w = t >> 6;
    const int l = lane & 15, g = lane >> 4;
    const int wm = w >> 1, wn = w & 1;
    const int bm = blockIdx.y * 128, bn = blockIdx.x * 64;

    f32x4 acc[2][2];
    #pragma unroll
    for (int mt = 0; mt < 2; ++mt)
        #pragma unroll
        for (int nt = 0; nt < 2; ++nt) acc[mt][nt] = (f32x4){0.f, 0.f, 0.f, 0.f};

    for (int kt = 0; kt < DMODEL; kt += 64) {
        __syncthreads();
        #pragma unroll
        for (int i = 0; i < 6; ++i) {
            const int sid = w * 6 + i;
            const ushort* src; ushort* dst; int rb, c;
            if (sid < 16)      { src = Ahg; dst = Ah; rb = bm; c = sid; }
            else if (sid < 32) { src = Alg; dst = Al; rb = bm; c = sid - 16; }
            else if (sid < 40) { src = Bhg; dst = Bh; rb = bn; c = sid - 32; }
            else               { src = Blg; dst = Bl; rb = bn; c = sid - 40; }
            const int row = c * 8 + (lane >> 3);
            const int sw = ((lane & 7) ^ (row & 7)) << 3;
            GLD16(src + (size_t)(rb + row) * DMODEL + kt + sw, dst + c * 512);
        }
        __syncthreads();

        bf16x8 ah[2][2], al[2][2], bhf[2][2], blf[2][2];
        #pragma unroll
        for (int mt = 0; mt < 2; ++mt)
            #pragma unroll
            for (int s = 0; s < 2; ++s) {
                const int m = wm * 32 + mt * 16 + l;
                const int off = m * 64 + (((g + 4 * s) ^ (m & 7)) << 3);
                ah[mt][s] = *reinterpret_cast<const bf16x8*>(&Ah[off]);
                al[mt][s] = *reinterpret_cast<const bf16x8*>(&Al[off]);
            }
        #pragma unroll
        for (int nt = 0; nt < 2; ++nt)
            #pragma unroll
            for (int s = 0; s < 2; ++s) {
                const int n = wn * 32 + nt * 16 + l;
                const int off = n * 64 + (((g + 4 * s) ^ (n & 7)) << 3);
                bhf[nt][s] = *reinterpret_cast<const bf16x8*>(&Bh[off]);
                blf[nt][s] = *reinterpret_cast<const bf16x8*>(&Bl[off]);
            }
        #pragma unroll
        for (int mt = 0; mt < 2; ++mt)
            #pragma unroll
            for (int nt = 0; nt < 2; ++nt)
                #pragma unroll
                for (int s = 0; s < 2; ++s) {
                    acc[mt][nt] = __builtin_amdgcn_mfma_f32_16x16x32_bf16(ah[mt][s], bhf[nt][s], acc[mt][nt], 0, 0, 0);
                    acc[mt][nt] = __builtin_amdgcn_mfma_f32_16x16x32_bf16(ah[mt][s], blf[nt][s], acc[mt][nt], 0, 0, 0);
                    acc[mt][nt] = __builtin_amdgcn_mfma_f32_16x16x32_bf16(al[mt][s], bhf[nt][s], acc[mt][nt], 0, 0, 0);
                }
    }

    #pragma unroll
    for (int mt = 0; mt < 2; ++mt)
        #pragma unroll
        for (int nt = 0; nt < 2; ++nt)
            #pragma unroll
            for (int r = 0; r < 4; ++r) {
                const int row = bm + wm * 32 + mt * 16 + g * 4 + r;
                const int col = bn + wn * 32 + nt * 16 + l;
                C[(size_t)row * DMODEL + col] = acc[mt][nt][r];
            }
}

// ---------------- launch ----------------
extern "C" void kernel_launch(void* const* d_in, const int* in_sizes, int n_in,
                              void* d_out, int out_size, void* d_ws, size_t ws_size,
                              hipStream_t stream) {
    const float* x  = (const float*)d_in[0];
    const float* Wq = (const float*)d_in[1];
    const float* Wk = (const float*)d_in[2];
    const float* Wv = (const float*)d_in[3];
    const float* Wo = (const float*)d_in[4];
    float* out = (float*)d_out;

    char* ws = (char*)d_ws;
    const size_t MB = 1024 * 1024;
    ushort* xh  = (ushort*)(ws);              // 8 MB  (aliased as ATh after QKV gemm)
    ushort* ath = xh;
    ushort* atl = (ushort*)(ws + 8 * MB);     // 8 MB
    ushort* wtc = (ushort*)(ws + 16 * MB);    // 6 MB  [3072][1024]
    ushort* woh = (ushort*)(ws + 22 * MB);    // 2 MB
    ushort* wol = (ushort*)(ws + 24 * MB);    // 2 MB
    ushort* Qb  = (ushort*)(ws + 26 * MB);    // 8 MB
    ushort* Kb  = (ushort*)(ws + 34 * MB);    // 8 MB
    ushort* Vtb = (ushort*)(ws + 42 * MB);    // 8 MB

    split_x<<<1024, 256, 0, stream>>>(x, xh, MROWS * DMODEL / 4);
    tsplit_w<<<dim3(16, 16, 4), 256, 0, stream>>>(Wq, Wk, Wv, Wo, wtc, woh, wol);

    gemm_qkv<<<dim3(24, 32), 512, 0, stream>>>(xh, wtc, Qb, Kb, Vtb);

    attn<<<dim3(64, 32), 256, 0, stream>>>(Qb, Kb, Vtb, ath, atl);

    gemm_o<<<dim3(16, 32), 512, 0, stream>>>(ath, atl, woh, wol, out);
}

// Round 8
// 187.902 us; speedup vs baseline: 1.1294x; 1.1294x over previous
//
#include <hip/hip_runtime.h>
#include <math.h>

#define BATCH 2
#define SEQ   2048
#define DMODEL 1024
#define NHEAD 16
#define HEADD 64
#define MROWS 4096

typedef __attribute__((ext_vector_type(8))) __bf16 bf16x8;
typedef __attribute__((ext_vector_type(4))) float f32x4;

__device__ __forceinline__ ushort f2bf(float f) {
    uint u = __float_as_uint(f);
    u += 0x7fffu + ((u >> 16) & 1u);
    return (ushort)(u >> 16);
}
__device__ __forceinline__ float bf2f(ushort h) {
    return __uint_as_float(((uint)h) << 16);
}
__device__ __forceinline__ ushort4 pack4bf(float a, float b, float c, float d) {
    union { __bf16 h[4]; ushort4 u; } p;
    p.h[0] = (__bf16)a; p.h[1] = (__bf16)b; p.h[2] = (__bf16)c; p.h[3] = (__bf16)d;
    return p.u;
}
__device__ __forceinline__ float vmax4(const f32x4 v) {
    return fmaxf(fmaxf(v[0], v[1]), fmaxf(v[2], v[3]));
}

#define GLD16(gsrc, ldst)                                                         \
    __builtin_amdgcn_global_load_lds(                                             \
        (const __attribute__((address_space(1))) unsigned int*)(gsrc),            \
        (__attribute__((address_space(3))) unsigned int*)(ldst), 16, 0, 0)

// Q pre-scale: (1/sqrt(64)) * log2(e)  -> softmax in exp2 domain
#define QSCALE 0.1803368801111204f

// ---------------- prep: x fp32 -> bf16 (hi only) ----------------
__global__ __launch_bounds__(256) void split_x(const float* __restrict__ in,
                                               ushort* __restrict__ oh, int n4) {
    int i = blockIdx.x * 256 + threadIdx.x;
    const int stride = gridDim.x * 256;
    for (; i < n4; i += stride) {
        const float4 v = reinterpret_cast<const float4*>(in)[i];
        ushort4 h;
        h.x = f2bf(v.x); h.y = f2bf(v.y); h.z = f2bf(v.z); h.w = f2bf(v.w);
        reinterpret_cast<ushort4*>(oh)[i] = h;
    }
}

// ---------------- prep: W^T; z<3 -> combined QKV hi; z==3 -> Wo hi/lo ----------------
__global__ __launch_bounds__(256) void tsplit_w(const float* __restrict__ Wq,
                                                const float* __restrict__ Wk,
                                                const float* __restrict__ Wv,
                                                const float* __restrict__ Wo,
                                                ushort* __restrict__ wtc,
                                                ushort* __restrict__ woh,
                                                ushort* __restrict__ wol) {
    const int z = blockIdx.z;
    const float* W = (z == 0) ? Wq : (z == 1) ? Wk : (z == 2) ? Wv : Wo;
    __shared__ float T[64][68];
    const int t = threadIdx.x;
    const int k0 = blockIdx.y * 64, n0 = blockIdx.x * 64;
    {
        const int r = t >> 2, c0 = (t & 3) * 16;
        #pragma unroll
        for (int j = 0; j < 4; ++j)
            *reinterpret_cast<float4*>(&T[r][c0 + j * 4]) =
                *reinterpret_cast<const float4*>(&W[(size_t)(k0 + r) * DMODEL + n0 + c0 + j * 4]);
    }
    __syncthreads();
    const int nl = t >> 2, kq = t & 3;
    if (z < 3) {
        ushort hb[16];
        #pragma unroll
        for (int e = 0; e < 16; ++e) hb[e] = f2bf(T[kq * 16 + e][nl]);
        const size_t o = (size_t)(z * 1024 + n0 + nl) * DMODEL + k0 + kq * 16;
        *reinterpret_cast<uint4*>(&wtc[o]) = *reinterpret_cast<uint4*>(&hb[0]);
        *reinterpret_cast<uint4*>(&wtc[o + 8]) = *reinterpret_cast<uint4*>(&hb[8]);
    } else {
        ushort hb[16], lb[16];
        #pragma unroll
        for (int e = 0; e < 16; ++e) {
            const float v = T[kq * 16 + e][nl];
            const ushort h = f2bf(v);
            hb[e] = h; lb[e] = f2bf(v - bf2f(h));
        }
        const size_t o = (size_t)(n0 + nl) * DMODEL + k0 + kq * 16;
        *reinterpret_cast<uint4*>(&woh[o]) = *reinterpret_cast<uint4*>(&hb[0]);
        *reinterpret_cast<uint4*>(&woh[o + 8]) = *reinterpret_cast<uint4*>(&hb[8]);
        *reinterpret_cast<uint4*>(&wol[o]) = *reinterpret_cast<uint4*>(&lb[0]);
        *reinterpret_cast<uint4*>(&wol[o + 8]) = *reinterpret_cast<uint4*>(&lb[8]);
    }
}

// ---------------- fused QKV GEMM: single-pass bf16, 128x128 tile, BK=64 ----------------
__global__ __launch_bounds__(512) void gemm_qkv(const ushort* __restrict__ xh,
                                                const ushort* __restrict__ wtc,
                                                ushort* __restrict__ Qb,
                                                ushort* __restrict__ Kb,
                                                ushort* __restrict__ Vtb) {
    __shared__ ushort SH[17408];
    ushort* const Ah = SH;
    ushort* const Bh = SH + 8192;

    const int t = threadIdx.x, lane = t & 63, w = t >> 6;
    const int l = lane & 15, g = lane >> 4;
    const int wm = w >> 2, wn = w & 3;
    const int bm = blockIdx.y * 128, bn = blockIdx.x * 128;

    f32x4 acc[4][2];
    #pragma unroll
    for (int mt = 0; mt < 4; ++mt)
        #pragma unroll
        for (int nt = 0; nt < 2; ++nt) acc[mt][nt] = (f32x4){0.f, 0.f, 0.f, 0.f};

    for (int kt = 0; kt < DMODEL; kt += 64) {
        __syncthreads();
        #pragma unroll
        for (int i = 0; i < 4; ++i) {
            const int sid = w * 4 + i;
            const int c = sid & 15;
            const ushort* src = (sid < 16) ? xh : wtc;
            const int rb = (sid < 16) ? bm : bn;
            ushort* dst = ((sid < 16) ? Ah : Bh) + c * 512;
            const int row = c * 8 + (lane >> 3);
            const int sw = ((lane & 7) ^ (row & 7)) << 3;
            GLD16(src + (size_t)(rb + row) * DMODEL + kt + sw, dst);
        }
        __syncthreads();

        bf16x8 af[4][2], bf[2][2];
        #pragma unroll
        for (int mt = 0; mt < 4; ++mt)
            #pragma unroll
            for (int s = 0; s < 2; ++s) {
                const int m = wm * 64 + mt * 16 + l;
                af[mt][s] = *reinterpret_cast<const bf16x8*>(&Ah[m * 64 + (((g + 4 * s) ^ (m & 7)) << 3)]);
            }
        #pragma unroll
        for (int nt = 0; nt < 2; ++nt)
            #pragma unroll
            for (int s = 0; s < 2; ++s) {
                const int n = wn * 32 + nt * 16 + l;
                bf[nt][s] = *reinterpret_cast<const bf16x8*>(&Bh[n * 64 + (((g + 4 * s) ^ (n & 7)) << 3)]);
            }
        #pragma unroll
        for (int mt = 0; mt < 4; ++mt)
            #pragma unroll
            for (int nt = 0; nt < 2; ++nt)
                #pragma unroll
                for (int s = 0; s < 2; ++s)
                    acc[mt][nt] = __builtin_amdgcn_mfma_f32_16x16x32_bf16(af[mt][s], bf[nt][s], acc[mt][nt], 0, 0, 0);
    }

    const int mode = bn >> 10;
    if (mode == 0) {
        #pragma unroll
        for (int mt = 0; mt < 4; ++mt)
            #pragma unroll
            for (int nt = 0; nt < 2; ++nt)
                #pragma unroll
                for (int r = 0; r < 4; ++r) {
                    const int row = bm + wm * 64 + mt * 16 + g * 4 + r;
                    const int col = bn + wn * 32 + nt * 16 + l;
                    Qb[(size_t)row * DMODEL + col] = f2bf(acc[mt][nt][r] * QSCALE);
                }
    } else if (mode == 1) {
        #pragma unroll
        for (int mt = 0; mt < 4; ++mt)
            #pragma unroll
            for (int nt = 0; nt < 2; ++nt)
                #pragma unroll
                for (int r = 0; r < 4; ++r) {
                    const int row = bm + wm * 64 + mt * 16 + g * 4 + r;
                    const int col = (bn - 1024) + wn * 32 + nt * 16 + l;
                    Kb[(size_t)row * DMODEL + col] = f2bf(acc[mt][nt][r]);
                }
    } else {
        __syncthreads();
        ushort* VtL = SH;   // [128 d][136 key]
        #pragma unroll
        for (int mt = 0; mt < 4; ++mt)
            #pragma unroll
            for (int nt = 0; nt < 2; ++nt)
                #pragma unroll
                for (int r = 0; r < 4; ++r) {
                    const int dl = wn * 32 + nt * 16 + l;
                    const int kl = wm * 64 + mt * 16 + g * 4 + r;
                    VtL[dl * 136 + kl] = f2bf(acc[mt][nt][r]);
                }
        __syncthreads();
        const int dl = t >> 2, kq = t & 3;
        const int b = bm >> 11;
        const int row = b * 1024 + (bn - 2048) + dl;
        const int key0 = bm & 2047;
        const size_t o = (size_t)row * SEQ + key0 + kq * 32;
        #pragma unroll
        for (int j = 0; j < 4; ++j)
            *reinterpret_cast<uint4*>(&Vtb[o + j * 8]) =
                *reinterpret_cast<uint4*>(&VtL[dl * 136 + kq * 32 + j * 8]);
    }
}

// ---------------- attention: paired tiles, pipelined K/V, XCD-local bh ----------------
// Grid (x=bh 32, y=pair 16): XCD = blockIdx.x % 8 -> each XCD serves 4 bh groups
// (2 MB K+V, L2-resident). Block = 256 thr (4 waves); wave w owns 16 rows of tile
// pair (set 0) and 16 rows of tile 31-pair (set 1), sharing K/V register frags.
#define LDP 72

__global__ __launch_bounds__(256, 2) void attn(const ushort* __restrict__ Q,
                                               const ushort* __restrict__ K,
                                               const ushort* __restrict__ Vt,
                                               ushort* __restrict__ ATh,
                                               ushort* __restrict__ ATl) {
    __shared__ ushort Pl[128 * LDP];   // wave-private rows

    const int t = threadIdx.x, lane = t & 63, w = t >> 6;
    const int l = lane & 15, g = lane >> 4;
    const int pair = blockIdx.y;                  // 0..15
    const int tA = pair, tB = 31 - pair;
    const int bh = blockIdx.x, b = bh >> 4, h = bh & 15;
    const size_t kbase = (size_t)b * SEQ * DMODEL + h * 64;
    const size_t vbase = (size_t)bh * 64 * SEQ;
    const int qrow0[2] = {tA * 64 + w * 16, tB * 64 + w * 16};
    const int nchA = tA + 1, nchB = tB + 1;       // nchA <= 16 < nchB

    // Q B-operand frags (col=q=lane&15, k=d=32s+8g+e) for both sets
    bf16x8 qf[2][2];
    #pragma unroll
    for (int qs = 0; qs < 2; ++qs) {
        const size_t qo = (size_t)(b * SEQ + qrow0[qs] + l) * DMODEL + h * 64 + 8 * g;
        qf[qs][0] = *reinterpret_cast<const bf16x8*>(&Q[qo]);
        qf[qs][1] = *reinterpret_cast<const bf16x8*>(&Q[qo + 32]);
    }

    f32x4 accO[2][4];
    #pragma unroll
    for (int qs = 0; qs < 2; ++qs)
        #pragma unroll
        for (int dt = 0; dt < 4; ++dt) accO[qs][dt] = (f32x4){0.f, 0.f, 0.f, 0.f};
    float m_i[2] = {-INFINITY, -INFINITY}, l_i[2] = {0.f, 0.f};

    bf16x8 kf[4][2], vf[4][2];

    // prologue: issue K(0)
    #pragma unroll
    for (int nt = 0; nt < 4; ++nt) {
        const size_t ko = kbase + (size_t)(nt * 16 + l) * DMODEL + 8 * g;
        kf[nt][0] = *reinterpret_cast<const bf16x8*>(&K[ko]);
        kf[nt][1] = *reinterpret_cast<const bf16x8*>(&K[ko + 32]);
    }

    for (int kc = 0; kc < nchB; ++kc) {
        const int k0 = kc * 64;
        const bool doA = (kc < nchA);

        // issue V(kc) early — consumed after softmax
        #pragma unroll
        for (int dt = 0; dt < 4; ++dt) {
            const size_t vo = vbase + (size_t)(dt * 16 + l) * SEQ + k0 + 8 * g;
            vf[dt][0] = *reinterpret_cast<const bf16x8*>(&Vt[vo]);
            vf[dt][1] = *reinterpret_cast<const bf16x8*>(&Vt[vo + 32]);
        }

        // swapped QK^T: sc[qs][nt][r] = score[key=k0+16nt+4g+r][q=qrow0+l]
        f32x4 sc[2][4];
        #pragma unroll
        for (int nt = 0; nt < 4; ++nt) {
            f32x4 z = (f32x4){0.f, 0.f, 0.f, 0.f};
            z = __builtin_amdgcn_mfma_f32_16x16x32_bf16(kf[nt][0], qf[1][0], z, 0, 0, 0);
            z = __builtin_amdgcn_mfma_f32_16x16x32_bf16(kf[nt][1], qf[1][1], z, 0, 0, 0);
            sc[1][nt] = z;
        }
        if (doA) {
            #pragma unroll
            for (int nt = 0; nt < 4; ++nt) {
                f32x4 z = (f32x4){0.f, 0.f, 0.f, 0.f};
                z = __builtin_amdgcn_mfma_f32_16x16x32_bf16(kf[nt][0], qf[0][0], z, 0, 0, 0);
                z = __builtin_amdgcn_mfma_f32_16x16x32_bf16(kf[nt][1], qf[0][1], z, 0, 0, 0);
                sc[0][nt] = z;
            }
        }

        // prefetch next chunk's K (hides under softmax+PV)
        if (kc + 1 < nchB) {
            const int kn = k0 + 64;
            #pragma unroll
            for (int nt = 0; nt < 4; ++nt) {
                const size_t ko = kbase + (size_t)(kn + nt * 16 + l) * DMODEL + 8 * g;
                kf[nt][0] = *reinterpret_cast<const bf16x8*>(&K[ko]);
                kf[nt][1] = *reinterpret_cast<const bf16x8*>(&K[ko + 32]);
            }
        }

        // causal mask on each set's diagonal chunk
        #pragma unroll
        for (int qs = 0; qs < 2; ++qs) {
            if (kc == ((qs == 0) ? nchA : nchB) - 1) {
                const int qg = qrow0[qs] + l;
                #pragma unroll
                for (int nt = 0; nt < 4; ++nt)
                    #pragma unroll
                    for (int r = 0; r < 4; ++r)
                        if (k0 + nt * 16 + g * 4 + r > qg) sc[qs][nt][r] = -INFINITY;
            }
        }

        // online softmax (exp2 domain), tree reductions, per active set
        #pragma unroll
        for (int qs = 0; qs < 2; ++qs) {
            if (qs == 0 && !doA) continue;
            float mc = fmaxf(fmaxf(vmax4(sc[qs][0]), vmax4(sc[qs][1])),
                             fmaxf(vmax4(sc[qs][2]), vmax4(sc[qs][3])));
            mc = fmaxf(mc, __shfl_xor(mc, 16, 64));
            mc = fmaxf(mc, __shfl_xor(mc, 32, 64));

            if (__any(mc > m_i[qs] + 8.f)) {          // defer-max rescale
                const float mn = fmaxf(m_i[qs], mc);
                const float al = exp2f(m_i[qs] - mn);
                m_i[qs] = mn;
                l_i[qs] *= al;
                #pragma unroll
                for (int r = 0; r < 4; ++r) {
                    const float ar = __shfl(al, 4 * g + r, 64);
                    #pragma unroll
                    for (int dt = 0; dt < 4; ++dt) accO[qs][dt][r] *= ar;
                }
            }

            float psum[4];
            #pragma unroll
            for (int nt = 0; nt < 4; ++nt) {
                #pragma unroll
                for (int r = 0; r < 4; ++r)
                    sc[qs][nt][r] = exp2f(sc[qs][nt][r] - m_i[qs]);
                psum[nt] = (sc[qs][nt][0] + sc[qs][nt][1]) + (sc[qs][nt][2] + sc[qs][nt][3]);
            }
            float rs = (psum[0] + psum[1]) + (psum[2] + psum[3]);
            rs += __shfl_xor(rs, 16, 64);
            rs += __shfl_xor(rs, 32, 64);
            l_i[qs] += rs;

            const int prow = w * 32 + qs * 16 + l;
            #pragma unroll
            for (int nt = 0; nt < 4; ++nt)
                *reinterpret_cast<ushort4*>(&Pl[prow * LDP + nt * 16 + 4 * g]) =
                    pack4bf(sc[qs][nt][0], sc[qs][nt][1], sc[qs][nt][2], sc[qs][nt][3]);
        }

        // PV (waits V; next-K still in flight)
        #pragma unroll
        for (int qs = 0; qs < 2; ++qs) {
            if (qs == 0 && !doA) continue;
            bf16x8 pf[2];
            const int prow = w * 32 + qs * 16 + l;
            pf[0] = *reinterpret_cast<const bf16x8*>(&Pl[prow * LDP + 8 * g]);
            pf[1] = *reinterpret_cast<const bf16x8*>(&Pl[prow * LDP + 32 + 8 * g]);
            #pragma unroll
            for (int dt = 0; dt < 4; ++dt) {
                accO[qs][dt] = __builtin_amdgcn_mfma_f32_16x16x32_bf16(pf[0], vf[dt][0], accO[qs][dt], 0, 0, 0);
                accO[qs][dt] = __builtin_amdgcn_mfma_f32_16x16x32_bf16(pf[1], vf[dt][1], accO[qs][dt], 0, 0, 0);
            }
        }
    }

    // epilogue: normalize, emit attended hi/lo bf16
    #pragma unroll
    for (int qs = 0; qs < 2; ++qs) {
        #pragma unroll
        for (int r = 0; r < 4; ++r) {
            const float lr = __shfl(l_i[qs], 4 * g + r, 64);
            const float inv = 1.f / lr;
            const size_t row = (size_t)(b * SEQ + qrow0[qs] + g * 4 + r) * DMODEL + h * 64;
            #pragma unroll
            for (int dt = 0; dt < 4; ++dt) {
                const float val = accO[qs][dt][r] * inv;
                const ushort hh = f2bf(val);
                ATh[row + dt * 16 + l] = hh;
                ATl[row + dt * 16 + l] = f2bf(val - bf2f(hh));
            }
        }
    }
}

// ---------------- out GEMM: 3-pass hi/lo, 128x64 tile, BK=64, fp32 out ----------------
__global__ __launch_bounds__(512) void gemm_o(const ushort* __restrict__ Ahg,
                                              const ushort* __restrict__ Alg,
                                              const ushort* __restrict__ Bhg,
                                              const ushort* __restrict__ Blg,
                                              float* __restrict__ C) {
    __shared__ ushort SH[24576];
    ushort* const Ah = SH;
    ushort* const Al = SH + 8192;
    ushort* const Bh = SH + 16384;
    ushort* const Bl = SH + 20480;

    const int t = threadIdx.x, lane = t & 63, w = t >> 6;
    const int l = lane & 15, g = lane >> 4;
    const int wm = w >> 1, wn = w & 1;
    const int bm = blockIdx.y * 128, bn = blockIdx.x * 64;

    f32x4 acc[2][2];
    #pragma unroll
    for (int mt = 0; mt < 2; ++mt)
        #pragma unroll
        for (int nt = 0; nt < 2; ++nt) acc[mt][nt] = (f32x4){0.f, 0.f, 0.f, 0.f};

    for (int kt = 0; kt < DMODEL; kt += 64) {
        __syncthreads();
        #pragma unroll
        for (int i = 0; i < 6; ++i) {
            const int sid = w * 6 + i;
            const ushort* src; ushort* dst; int rb, c;
            if (sid < 16)      { src = Ahg; dst = Ah; rb = bm; c = sid; }
            else if (sid < 32) { src = Alg; dst = Al; rb = bm; c = sid - 16; }
            else if (sid < 40) { src = Bhg; dst = Bh; rb = bn; c = sid - 32; }
            else               { src = Blg; dst = Bl; rb = bn; c = sid - 40; }
            const int row = c * 8 + (lane >> 3);
            const int sw = ((lane & 7) ^ (row & 7)) << 3;
            GLD16(src + (size_t)(rb + row) * DMODEL + kt + sw, dst + c * 512);
        }
        __syncthreads();

        bf16x8 ah[2][2], al[2][2], bhf[2][2], blf[2][2];
        #pragma unroll
        for (int mt = 0; mt < 2; ++mt)
            #pragma unroll
            for (int s = 0; s < 2; ++s) {
                const int m = wm * 32 + mt * 16 + l;
                const int off = m * 64 + (((g + 4 * s) ^ (m & 7)) << 3);
                ah[mt][s] = *reinterpret_cast<const bf16x8*>(&Ah[off]);
                al[mt][s] = *reinterpret_cast<const bf16x8*>(&Al[off]);
            }
        #pragma unroll
        for (int nt = 0; nt < 2; ++nt)
            #pragma unroll
            for (int s = 0; s < 2; ++s) {
                const int n = wn * 32 + nt * 16 + l;
                const int off = n * 64 + (((g + 4 * s) ^ (n & 7)) << 3);
                bhf[nt][s] = *reinterpret_cast<const bf16x8*>(&Bh[off]);
                blf[nt][s] = *reinterpret_cast<const bf16x8*>(&Bl[off]);
            }
        #pragma unroll
        for (int mt = 0; mt < 2; ++mt)
            #pragma unroll
            for (int nt = 0; nt < 2; ++nt)
                #pragma unroll
                for (int s = 0; s < 2; ++s) {
                    acc[mt][nt] = __builtin_amdgcn_mfma_f32_16x16x32_bf16(ah[mt][s], bhf[nt][s], acc[mt][nt], 0, 0, 0);
                    acc[mt][nt] = __builtin_amdgcn_mfma_f32_16x16x32_bf16(ah[mt][s], blf[nt][s], acc[mt][nt], 0, 0, 0);
                    acc[mt][nt] = __builtin_amdgcn_mfma_f32_16x16x32_bf16(al[mt][s], bhf[nt][s], acc[mt][nt], 0, 0, 0);
                }
    }

    #pragma unroll
    for (int mt = 0; mt < 2; ++mt)
        #pragma unroll
        for (int nt = 0; nt < 2; ++nt)
            #pragma unroll
            for (int r = 0; r < 4; ++r) {
                const int row = bm + wm * 32 + mt * 16 + g * 4 + r;
                const int col = bn + wn * 32 + nt * 16 + l;
                C[(size_t)row * DMODEL + col] = acc[mt][nt][r];
            }
}

// ---------------- launch ----------------
extern "C" void kernel_launch(void* const* d_in, const int* in_sizes, int n_in,
                              void* d_out, int out_size, void* d_ws, size_t ws_size,
                              hipStream_t stream) {
    const float* x  = (const float*)d_in[0];
    const float* Wq = (const float*)d_in[1];
    const float* Wk = (const float*)d_in[2];
    const float* Wv = (const float*)d_in[3];
    const float* Wo = (const float*)d_in[4];
    float* out = (float*)d_out;

    char* ws = (char*)d_ws;
    const size_t MB = 1024 * 1024;
    ushort* xh  = (ushort*)(ws);              // 8 MB  (aliased as ATh after QKV gemm)
    ushort* ath = xh;
    ushort* atl = (ushort*)(ws + 8 * MB);     // 8 MB
    ushort* wtc = (ushort*)(ws + 16 * MB);    // 6 MB  [3072][1024]
    ushort* woh = (ushort*)(ws + 22 * MB);    // 2 MB
    ushort* wol = (ushort*)(ws + 24 * MB);    // 2 MB
    ushort* Qb  = (ushort*)(ws + 26 * MB);    // 8 MB
    ushort* Kb  = (ushort*)(ws + 34 * MB);    // 8 MB
    ushort* Vtb = (ushort*)(ws + 42 * MB);    // 8 MB

    split_x<<<1024, 256, 0, stream>>>(x, xh, MROWS * DMODEL / 4);
    tsplit_w<<<dim3(16, 16, 4), 256, 0, stream>>>(Wq, Wk, Wv, Wo, wtc, woh, wol);

    gemm_qkv<<<dim3(24, 32), 512, 0, stream>>>(xh, wtc, Qb, Kb, Vtb);

    attn<<<dim3(32, 16), 256, 0, stream>>>(Qb, Kb, Vtb, ath, atl);

    gemm_o<<<dim3(16, 32), 512, 0, stream>>>(ath, atl, woh, wol, out);
}